// Round 4
// baseline (306.747 us; speedup 1.0000x reference)
//
#include <hip/hip_runtime.h>
#include <math.h>

#define S 16
#define C 8
#define N 5000
#define T 100
#define N4 1250   // N / 4 float4 columns

typedef float vfloat4 __attribute__((ext_vector_type(4)));

// ---------------- Prep kernel ----------------
// blocks 0..15  : emission log-softmax over nodes (row s = blockIdx.x)
// blocks 16..35 : chain log-softmax over chains (256 nodes per block)
// block  36     : HMM forward recursion in linear space (single wave)
__global__ __launch_bounds__(256) void prep_kernel(const float* __restrict__ u_init,
                                                   const float* __restrict__ u_cw,
                                                   const float* __restrict__ u_e,
                                                   const float* __restrict__ u_T,
                                                   float* __restrict__ ws_le,   // (S,N)
                                                   float* __restrict__ ws_lcw,  // (N,C)
                                                   float* __restrict__ ws_h,    // (T,S)
                                                   float* __restrict__ out_h) { // (T,S)
    const int b = blockIdx.x;
    const int tid = threadIdx.x;

    if (b < 16) {
        // ---- emission row log-softmax ----
        const float* row = u_e + b * N;
        __shared__ float red[256];
        float m = -INFINITY;
        for (int n = tid; n < N; n += 256) m = fmaxf(m, row[n]);
        red[tid] = m;
        __syncthreads();
        for (int o = 128; o > 0; o >>= 1) {
            if (tid < o) red[tid] = fmaxf(red[tid], red[tid + o]);
            __syncthreads();
        }
        m = red[0];
        __syncthreads();
        float sum = 0.f;
        for (int n = tid; n < N; n += 256) sum += expf(row[n] - m);
        red[tid] = sum;
        __syncthreads();
        for (int o = 128; o > 0; o >>= 1) {
            if (tid < o) red[tid] += red[tid + o];
            __syncthreads();
        }
        const float lse = m + logf(red[0]);
        for (int n = tid; n < N; n += 256) ws_le[b * N + n] = row[n] - lse;
    } else if (b < 36) {
        // ---- chain log-softmax ----
        const int n = (b - 16) * 256 + tid;
        if (n < N) {
            float v[C];
            float m = -INFINITY;
            for (int c = 0; c < C; ++c) {
                v[c] = u_cw[n * C + c];
                m = fmaxf(m, v[c]);
            }
            float s = 0.f;
            for (int c = 0; c < C; ++c) s += expf(v[c] - m);
            const float lse = m + logf(s);
            for (int c = 0; c < C; ++c) ws_lcw[n * C + c] = v[c] - lse;
        }
    } else {
        // ---- HMM forward recursion, linear space, single wave ----
        if (tid < S) {
            const int j = tid;
            float m = -INFINITY;
            for (int i = 0; i < S; ++i) m = fmaxf(m, u_init[i]);
            float ssum = 0.f;
            for (int i = 0; i < S; ++i) ssum += expf(u_init[i] - m);
            const float lse0 = m + logf(ssum);
            const float h0 = u_init[j] - lse0;
            out_h[j] = h0;
            ws_h[j] = h0;
            float mr = -INFINITY;
            for (int k = 0; k < S; ++k) mr = fmaxf(mr, u_T[j * S + k]);
            float sr = 0.f;
            for (int k = 0; k < S; ++k) sr += expf(u_T[j * S + k] - mr);
            const float lse_row = mr + logf(sr);
            float texp[S];
            #pragma unroll
            for (int i = 0; i < S; ++i) {
                const float lse_i = __shfl(lse_row, i, 64);
                texp[i] = expf(u_T[i * S + j] - lse_i);
            }
            float p = expf(h0);
            for (int t = 1; t < T; ++t) {
                float pn = 0.f;
                #pragma unroll
                for (int i = 0; i < S; ++i) {
                    pn = fmaf(__shfl(p, i, 64), texp[i], pn);
                }
                p = pn;
                const float hv = logf(p);
                out_h[t * S + j] = hv;
                ws_h[t * S + j] = hv;
            }
        }
    }
}

// ---------------- Perm kernel: 256 MB streaming write ----------------
// grid (5, S, T). Each thread: 1 le load + 8 lcw loads + 8 nontemporal float4 stores.
// out_perm[t][s][c][4i+k] = le[s][4i+k] + h[t][s] + lcw[4i+k][c]
__global__ __launch_bounds__(256) void perm_kernel(const vfloat4* __restrict__ le4,
                                                   const vfloat4* __restrict__ lcw4,
                                                   const float* __restrict__ ws_h,
                                                   vfloat4* __restrict__ outp4) {
    const int i = blockIdx.x * 256 + threadIdx.x;  // float4 column, 0..1249
    const int s = blockIdx.y;
    const int t = blockIdx.z;
    if (i >= N4) return;

    const float hval = ws_h[t * S + s];
    const vfloat4 e = le4[(size_t)s * N4 + i];
    const vfloat4 a = e + hval;

    // lc[c][k] = lcw[4i+k][c]: 32 contiguous floats at lcw4[8i .. 8i+7]
    float lc[C][4];
    #pragma unroll
    for (int j = 0; j < 8; ++j) {
        const vfloat4 v = lcw4[8 * (size_t)i + j];
        const int nl = j >> 1;
        const int cb = (j & 1) * 4;
        lc[cb + 0][nl] = v.x;
        lc[cb + 1][nl] = v.y;
        lc[cb + 2][nl] = v.z;
        lc[cb + 3][nl] = v.w;
    }

    const size_t base = (((size_t)t * S + s) * C) * N4 + i;
    #pragma unroll
    for (int c = 0; c < C; ++c) {
        vfloat4 w;
        w.x = a.x + lc[c][0];
        w.y = a.y + lc[c][1];
        w.z = a.z + lc[c][2];
        w.w = a.w + lc[c][3];
        __builtin_nontemporal_store(w, &outp4[base + (size_t)c * N4]);
    }
}

// ---------------- out0 kernel: (T,N) logsumexp over states ----------------
__global__ __launch_bounds__(256) void out0_kernel(const vfloat4* __restrict__ le4,
                                                   const float* __restrict__ ws_h,
                                                   vfloat4* __restrict__ out0_4) {
    const int t = blockIdx.y;
    const int i = blockIdx.x * 256 + threadIdx.x;
    __shared__ float h[S];
    if (threadIdx.x < S) h[threadIdx.x] = ws_h[t * S + threadIdx.x];
    __syncthreads();
    if (i >= N4) return;

    vfloat4 a[S];
    vfloat4 m4 = {-INFINITY, -INFINITY, -INFINITY, -INFINITY};
    #pragma unroll
    for (int s = 0; s < S; ++s) {
        const vfloat4 e = le4[(size_t)s * N4 + i];
        a[s] = e + h[s];
        m4.x = fmaxf(m4.x, a[s].x); m4.y = fmaxf(m4.y, a[s].y);
        m4.z = fmaxf(m4.z, a[s].z); m4.w = fmaxf(m4.w, a[s].w);
    }
    vfloat4 sum4 = {0.f, 0.f, 0.f, 0.f};
    #pragma unroll
    for (int s = 0; s < S; ++s) {
        sum4.x += expf(a[s].x - m4.x);
        sum4.y += expf(a[s].y - m4.y);
        sum4.z += expf(a[s].z - m4.z);
        sum4.w += expf(a[s].w - m4.w);
    }
    vfloat4 r;
    r.x = m4.x + logf(sum4.x);
    r.y = m4.y + logf(sum4.y);
    r.z = m4.z + logf(sum4.z);
    r.w = m4.w + logf(sum4.w);
    __builtin_nontemporal_store(r, &out0_4[(size_t)t * N4 + i]);
}

extern "C" void kernel_launch(void* const* d_in, const int* in_sizes, int n_in,
                              void* d_out, int out_size, void* d_ws, size_t ws_size,
                              hipStream_t stream) {
    const float* u_init = (const float*)d_in[0];   // (S,)
    const float* u_cw   = (const float*)d_in[1];   // (1,N,C)
    const float* u_e    = (const float*)d_in[2];   // (S,N)
    const float* u_T    = (const float*)d_in[3];   // (S,S)

    float* out = (float*)d_out;
    float* out0     = out;                                          // (T,N)
    float* out_perm = out + (size_t)T * N;                          // (T,S,C,N)
    float* out_h    = out + (size_t)T * N + (size_t)T * S * C * N;  // (T,S)

    float* ws  = (float*)d_ws;
    float* ws_h   = ws;                   // 1600 floats
    float* ws_le  = ws + 1600;            // 80000 floats (offset 6400 B, 16B-aligned)
    float* ws_lcw = ws + 1600 + 80000;    // 40000 floats (offset 326400 B, 16B-aligned)

    prep_kernel<<<37, 256, 0, stream>>>(u_init, u_cw, u_e, u_T, ws_le, ws_lcw, ws_h, out_h);
    perm_kernel<<<dim3(5, S, T), 256, 0, stream>>>((const vfloat4*)ws_le, (const vfloat4*)ws_lcw,
                                                   ws_h, (vfloat4*)out_perm);
    out0_kernel<<<dim3(5, T), 256, 0, stream>>>((const vfloat4*)ws_le, ws_h, (vfloat4*)out0);
}